// Round 5
// baseline (496.225 us; speedup 1.0000x reference)
//
#include <hip/hip_runtime.h>

// GAT (3-layer) on MI355X.
// R17: all three gather kernels (fused<8>, fused<2>, agg32) plateau at the
//      SAME ~2TB/s of L2-miss traffic = ~1 miss/cy/XCD fabric request-rate
//      ceiling (R16: unroll-4 neutral, occupancy-compensated; FETCH 154MB =
//      1.7M edges x 128B x 69% L2-miss). Fix = raise L2 hit rate:
//      srclist bucketed by SRC RANGE (8 ranges x 12.5K nodes, CAP_R=14
//      slots/range) and every agg loop walks ranges IN ORDER -> device-wide,
//      all lanes gather from the same ~1.6MB feature slice at a time, which
//      fits every XCD's 4MB L2. Misses -> compulsory only.
//      Falsifiable signal: fused FETCH must drop 154 -> <90MB.
//      Kept: R15 agg+gemm LDS fusion, ping-pong buffers, prep_cursor fold,
//      R14 fill form (now with per-(dst,range) cursors).

typedef unsigned short bfu;
typedef unsigned char u8;
typedef __attribute__((ext_vector_type(8))) short bf16x8;
typedef __attribute__((ext_vector_type(4))) float f32x4;
typedef __attribute__((ext_vector_type(2))) float f32x2;
typedef __attribute__((ext_vector_type(4))) int i32x4;

constexpr int N_NODES = 100000;
constexpr int E_IN    = 1600000;
constexpr int E_TOT   = E_IN + N_NODES;   // + self loops
constexpr float NEG   = 0.2f;
constexpr int P_XCD   = 8;
constexpr int PSZ     = N_NODES / P_XCD;  // 12500 (also the src-range size)
constexpr int NR      = 8;                // src ranges
constexpr int CAP_R   = 14;               // slots per (dst,range); Poisson(2.1)
constexpr int SL_STRIDE = NR * CAP_R;     // 112 ints per dst
constexpr int AGG32_B = N_NODES / 32;     // 3125
constexpr int GEMM_B  = (N_NODES + 63) / 64;        // 1563
constexpr int FUSE_B  = (N_NODES + 63) / 64;        // 1563 (64 dst rows/block)
constexpr int EDGE_B4 = (E_TOT / 4 + 255) / 256;    // 1661
constexpr int FILL_B  = EDGE_B4 * P_XCD;            // 13288
constexpr int PREP_ITEMS = 43008;
constexpr int PREP_B  = (PREP_ITEMS + 255) / 256;   // 168

__device__ inline bfu f2bf(float f) {
    union { float f; unsigned i; } c; c.f = f;
    unsigned x = c.i;
    return (bfu)((x + 0x7fffu + ((x >> 16) & 1u)) >> 16);
}
__device__ inline u8 f2fp8(float f) {
    return (u8)(__builtin_amdgcn_cvt_pk_fp8_f32(f, f, 0, false) & 0xff);
}

// ---------------- prep: W^T + folded logit columns (bf16) -------------------
// WtX1/WtX2: 144 rows x 128 k  (rows 0-127 = W^T; 128-135 = ws; 136-143 = wd)
// WtX3:      48 rows x 128 k   (rows 0-31 = W3^T; 32 = ws3; 33 = wd3; 34-47 = 0)

__device__ inline void prep_body(int idx,
        const float* __restrict__ W1, const float* __restrict__ W2,
        const float* __restrict__ W3,
        const float* __restrict__ as1, const float* __restrict__ ad1,
        const float* __restrict__ as2, const float* __restrict__ ad2,
        const float* __restrict__ as3, const float* __restrict__ ad3,
        bfu* __restrict__ WtX1, bfu* __restrict__ WtX2, bfu* __restrict__ WtX3) {
    if (idx < 16384) {
        int k = idx >> 7, n = idx & 127;
        WtX1[n * 128 + k] = f2bf(W1[idx]);
    } else if (idx < 32768) {
        int r = idx - 16384;
        int k = r >> 7, n = r & 127;
        WtX2[n * 128 + k] = f2bf(W2[r]);
    } else if (idx < 36864) {
        int r = idx - 32768;
        int k = r >> 5, n = r & 31;
        WtX3[n * 128 + k] = f2bf(W3[r]);
    } else if (idx < 38912) {          // layer-1 ws/wd: 2 x 8h x 128k
        int r = idx - 36864;
        int sd = r >> 10, rr = r & 1023;
        int h = rr >> 7, k = rr & 127;
        const float* a = sd ? ad1 : as1;
        float v = 0.f;
        #pragma unroll
        for (int c = 0; c < 16; ++c) v += W1[k * 128 + h * 16 + c] * a[h * 16 + c];
        WtX1[(128 + sd * 8 + h) * 128 + k] = f2bf(v);
    } else if (idx < 40960) {          // layer-2 ws/wd
        int r = idx - 38912;
        int sd = r >> 10, rr = r & 1023;
        int h = rr >> 7, k = rr & 127;
        const float* a = sd ? ad2 : as2;
        float v = 0.f;
        #pragma unroll
        for (int c = 0; c < 16; ++c) v += W2[k * 128 + h * 16 + c] * a[h * 16 + c];
        WtX2[(128 + sd * 8 + h) * 128 + k] = f2bf(v);
    } else if (idx < 41216) {          // layer-3 ws/wd: 2 x 128k
        int r = idx - 40960;
        int sd = r >> 7, k = r & 127;
        const float* a = sd ? ad3 : as3;
        float v = 0.f;
        #pragma unroll
        for (int c = 0; c < 32; ++c) v += W3[k * 32 + c] * a[c];
        WtX3[(32 + sd) * 128 + k] = f2bf(v);
    } else if (idx < 43008) {          // zero rows 34-47 of WtX3
        WtX3[34 * 128 + (idx - 41216)] = 0;
    }
}

// prep + cursor-zero + out-zero in one tiny dispatch (replaces 2 memsets).
__global__ __launch_bounds__(256) void prep_cursor(
        const float* __restrict__ W1, const float* __restrict__ W2,
        const float* __restrict__ W3,
        const float* __restrict__ as1, const float* __restrict__ ad1,
        const float* __restrict__ as2, const float* __restrict__ ad2,
        const float* __restrict__ as3, const float* __restrict__ ad3,
        bfu* __restrict__ WtX1, bfu* __restrict__ WtX2, bfu* __restrict__ WtX3,
        int* __restrict__ cursor, float* __restrict__ outp) {
    int idx = blockIdx.x * 256 + threadIdx.x;
    prep_body(idx, W1, W2, W3, as1, ad1, as2, ad2, as3, ad3, WtX1, WtX2, WtX3);
    for (int i = idx; i < N_NODES * NR; i += PREP_ITEMS) cursor[i] = 0;
    if (idx < 32) outp[idx] = 0.f;
}

// ---------------- fill (dst-partitioned, src-range bucketed) ----------------

__global__ __launch_bounds__(256) void fill(const int* __restrict__ ei,
        int* __restrict__ cursor, int* __restrict__ srclist) {
    int p = blockIdx.x & 7;
    int b = blockIdx.x >> 3;
    int lo = p * PSZ, hi = lo + PSZ;
    int e0 = (b * 256 + threadIdx.x) * 4;
    if (e0 >= E_TOT) return;
    bool self = e0 >= E_IN;
    i32x4 d4, s4;
    if (!self) {
        d4 = __builtin_nontemporal_load((const i32x4*)&ei[E_IN + e0]);
        s4 = __builtin_nontemporal_load((const i32x4*)&ei[e0]);
    } else {
        int bb = e0 - E_IN;
        d4[0] = bb; d4[1] = bb + 1; d4[2] = bb + 2; d4[3] = bb + 3;
        s4 = d4;
    }
    #pragma unroll
    for (int q = 0; q < 4; ++q) {
        int d = d4[q];
        if (d >= lo && d < hi) {
            int s = s4[q];
            int r = s / PSZ;                         // src range (magic-mul)
            int pos = atomicAdd(&cursor[d * NR + r], 1);
            if (pos < CAP_R)
                srclist[(size_t)d * SL_STRIDE + r * CAP_R + pos] = s;
        }
    }
}

// ---------------- MFMA GEMM (layer 1 only), logits as extra B-tile ----------
// C/D layout: row = quad*4+r, col = nt*16+m.

__device__ inline bf16x8 ldcvt_f32(const float* p) {
    float4 v0 = *(const float4*)p;
    float4 v1 = *(const float4*)(p + 4);
    bf16x8 a;
    a[0] = (short)f2bf(v0.x); a[1] = (short)f2bf(v0.y);
    a[2] = (short)f2bf(v0.z); a[3] = (short)f2bf(v0.w);
    a[4] = (short)f2bf(v1.x); a[5] = (short)f2bf(v1.y);
    a[6] = (short)f2bf(v1.z); a[7] = (short)f2bf(v1.w);
    return a;
}

__global__ __launch_bounds__(256) void gemm_mfma_l1(const float* __restrict__ Xg,
                                                    const bfu* __restrict__ Wt,
                                                    u8* __restrict__ Y,
                                                    float* __restrict__ als,
                                                    float* __restrict__ ald) {
    constexpr int NTO = 8;
    constexpr int COUT = 128;
    int wid  = threadIdx.x >> 6;
    int lane = threadIdx.x & 63;
    int m = lane & 15, quad = lane >> 4;
    int rbase = (blockIdx.x * 4 + wid) * 16;
    if (rbase >= N_NODES) return;
    int rA = rbase + m; if (rA >= N_NODES) rA = N_NODES - 1;

    const float* Ap = Xg + (size_t)rA * 128 + quad * 8;
    bf16x8 a0 = ldcvt_f32(Ap);
    bf16x8 a1 = ldcvt_f32(Ap + 32);
    bf16x8 a2 = ldcvt_f32(Ap + 64);
    bf16x8 a3 = ldcvt_f32(Ap + 96);

    const bfu* Bp = Wt + (size_t)m * 128 + quad * 8;
    f32x4 acc[NTO + 1];
    #pragma unroll
    for (int nt = 0; nt <= NTO; nt++) {
        const bfu* Bn = Bp + nt * 16 * 128;
        f32x4 c = {0.f, 0.f, 0.f, 0.f};
        c = __builtin_amdgcn_mfma_f32_16x16x32_bf16(a0, *(const bf16x8*)(Bn),      c, 0, 0, 0);
        c = __builtin_amdgcn_mfma_f32_16x16x32_bf16(a1, *(const bf16x8*)(Bn + 32), c, 0, 0, 0);
        c = __builtin_amdgcn_mfma_f32_16x16x32_bf16(a2, *(const bf16x8*)(Bn + 64), c, 0, 0, 0);
        c = __builtin_amdgcn_mfma_f32_16x16x32_bf16(a3, *(const bf16x8*)(Bn + 96), c, 0, 0, 0);
        acc[nt] = c;
    }

    #pragma unroll
    for (int nt = 0; nt < NTO; nt++) {
        #pragma unroll
        for (int r = 0; r < 4; r++) {
            int row = rbase + quad * 4 + r;
            if (row < N_NODES)
                Y[(size_t)row * COUT + nt * 16 + m] = f2fp8(acc[nt][r]);
        }
    }
    #pragma unroll
    for (int r = 0; r < 4; r++) {
        int row = rbase + quad * 4 + r;
        if (row >= N_NODES) continue;
        float v = acc[NTO][r];
        if (m < 8) als[row * 8 + m] = v;
        else       ald[row * 8 + (m - 8)] = v;
    }
}

// ---------------- fused agg + gemm ------------------------------------------
// Phase 1 (agg): 4 waves x 8 dst x 2 iters = 64 dst rows -> bf16 in LDS.
//   Gather walks the 8 src-range buckets IN ORDER (device-wide phase
//   alignment -> the active 1.6MB feature slice is L2-resident).
//   LDS: 64 rows x 16 granules(16B), swizzled gran ^= (row&7) both sides.
// Phase 2 (gemm): 64-row MFMA tile, A-frags from LDS, B = WtX (global).

__device__ inline void unpack_fma(uint4 u, float w, float* a) {
    f32x2 p;
    p = __builtin_amdgcn_cvt_pk_f32_fp8((int)u.x, false); a[0]=fmaf(w,p[0],a[0]);  a[1]=fmaf(w,p[1],a[1]);
    p = __builtin_amdgcn_cvt_pk_f32_fp8((int)u.x, true);  a[2]=fmaf(w,p[0],a[2]);  a[3]=fmaf(w,p[1],a[3]);
    p = __builtin_amdgcn_cvt_pk_f32_fp8((int)u.y, false); a[4]=fmaf(w,p[0],a[4]);  a[5]=fmaf(w,p[1],a[5]);
    p = __builtin_amdgcn_cvt_pk_f32_fp8((int)u.y, true);  a[6]=fmaf(w,p[0],a[6]);  a[7]=fmaf(w,p[1],a[7]);
    p = __builtin_amdgcn_cvt_pk_f32_fp8((int)u.z, false); a[8]=fmaf(w,p[0],a[8]);  a[9]=fmaf(w,p[1],a[9]);
    p = __builtin_amdgcn_cvt_pk_f32_fp8((int)u.z, true);  a[10]=fmaf(w,p[0],a[10]); a[11]=fmaf(w,p[1],a[11]);
    p = __builtin_amdgcn_cvt_pk_f32_fp8((int)u.w, false); a[12]=fmaf(w,p[0],a[12]); a[13]=fmaf(w,p[1],a[13]);
    p = __builtin_amdgcn_cvt_pk_f32_fp8((int)u.w, true);  a[14]=fmaf(w,p[0],a[14]); a[15]=fmaf(w,p[1],a[15]);
}

template<int NTO>
__global__ __launch_bounds__(256) void fused_agg_gemm(
        const u8* __restrict__ Hin,       // N x 128 fp8 (prev gemm out)
        const float* __restrict__ als_in, // N x 8
        const float* __restrict__ ald_in, // N x 8
        const int* __restrict__ deg, const int* __restrict__ srclist,
        const float* __restrict__ bias,   // 128 (prev layer bias)
        const bfu* __restrict__ Wt,       // (NTO+1)*16 x 128 bf16
        u8* __restrict__ Yout,            // N x NTO*16 fp8
        float* __restrict__ als_out, float* __restrict__ ald_out) {
    __shared__ uint4 ldsb[64 * 16];       // 16 KB
    int t    = threadIdx.x;
    int wid  = t >> 6;
    int lane = t & 63;
    int sub  = lane >> 3;
    int li   = lane & 7;
    int rbase = blockIdx.x * 64;

    // ---- phase 1: aggregate 64 dst nodes into LDS ----
    #pragma unroll
    for (int it = 0; it < 2; ++it) {
        int dl = wid * 16 + it * 8 + sub;          // 0..63
        int d  = rbase + dl;
        if (d < N_NODES) {
            int c0 = li * 16;
            float ad = ald_in[d * 8 + li];
            const int* sl = srclist + (size_t)d * SL_STRIDE;
            int cnt[8];
            *(i32x4*)&cnt[0] = *(const i32x4*)&deg[d * NR];
            *(i32x4*)&cnt[4] = *(const i32x4*)&deg[d * NR + 4];
            float a[16];
            #pragma unroll
            for (int k = 0; k < 16; ++k) a[k] = 0.f;
            float den = 0.f;
            for (int r = 0; r < NR; ++r) {
                int n = cnt[r]; n = n < CAP_R ? n : CAP_R;
                const int* slr = sl + r * CAP_R;
                int j = 0;
                for (; j + 2 <= n; j += 2) {
                    int s0 = slr[j], s1 = slr[j + 1];
                    uint4 u0 = *(const uint4*)(Hin + (size_t)s0 * 128 + c0);
                    uint4 u1 = *(const uint4*)(Hin + (size_t)s1 * 128 + c0);
                    float x0 = als_in[s0 * 8 + li], x1 = als_in[s1 * 8 + li];
                    float l0 = x0 + ad; l0 = fmaxf(l0, NEG * l0); float w0 = __expf(l0);
                    float l1 = x1 + ad; l1 = fmaxf(l1, NEG * l1); float w1 = __expf(l1);
                    den += w0 + w1;
                    unpack_fma(u0, w0, a);
                    unpack_fma(u1, w1, a);
                }
                if (j < n) {
                    int s0 = slr[j];
                    uint4 u0 = *(const uint4*)(Hin + (size_t)s0 * 128 + c0);
                    float x0 = als_in[s0 * 8 + li];
                    float l0 = x0 + ad; l0 = fmaxf(l0, NEG * l0); float w0 = __expf(l0);
                    den += w0;
                    unpack_fma(u0, w0, a);
                }
            }
            float r = 1.f / den;
            unsigned dw[8];
            #pragma unroll
            for (int k = 0; k < 8; ++k) {
                float e0 = fmaxf(fmaf(a[2*k],   r, bias[c0 + 2*k]),   0.f);
                float e1 = fmaxf(fmaf(a[2*k+1], r, bias[c0 + 2*k+1]), 0.f);
                dw[k] = (unsigned)f2bf(e0) | ((unsigned)f2bf(e1) << 16);
            }
            uint4 st0 = {dw[0], dw[1], dw[2], dw[3]};
            uint4 st1 = {dw[4], dw[5], dw[6], dw[7]};
            int sw = dl & 7;
            ldsb[dl * 16 + ((li * 2)     ^ sw)] = st0;
            ldsb[dl * 16 + ((li * 2 + 1) ^ sw)] = st1;
        }
    }
    __syncthreads();

    // ---- phase 2: 64-row MFMA gemm, A from LDS ----
    constexpr int COUT = NTO * 16;
    int m = lane & 15, quad = lane >> 4;
    int lr = wid * 16 + m;
    int lb = lr * 16, sw = lr & 7;
    bf16x8 a0 = *(const bf16x8*)&ldsb[lb + ((quad)      ^ sw)];
    bf16x8 a1 = *(const bf16x8*)&ldsb[lb + ((quad + 4)  ^ sw)];
    bf16x8 a2 = *(const bf16x8*)&ldsb[lb + ((quad + 8)  ^ sw)];
    bf16x8 a3 = *(const bf16x8*)&ldsb[lb + ((quad + 12) ^ sw)];

    const bfu* Bp = Wt + (size_t)m * 128 + quad * 8;
    f32x4 acc[NTO + 1];
    #pragma unroll
    for (int nt = 0; nt <= NTO; nt++) {
        const bfu* Bn = Bp + nt * 16 * 128;
        f32x4 c = {0.f, 0.f, 0.f, 0.f};
        c = __builtin_amdgcn_mfma_f32_16x16x32_bf16(a0, *(const bf16x8*)(Bn),      c, 0, 0, 0);
        c = __builtin_amdgcn_mfma_f32_16x16x32_bf16(a1, *(const bf16x8*)(Bn + 32), c, 0, 0, 0);
        c = __builtin_amdgcn_mfma_f32_16x16x32_bf16(a2, *(const bf16x8*)(Bn + 64), c, 0, 0, 0);
        c = __builtin_amdgcn_mfma_f32_16x16x32_bf16(a3, *(const bf16x8*)(Bn + 96), c, 0, 0, 0);
        acc[nt] = c;
    }

    #pragma unroll
    for (int nt = 0; nt < NTO; nt++) {
        #pragma unroll
        for (int r = 0; r < 4; r++) {
            int row = rbase + wid * 16 + quad * 4 + r;
            if (row < N_NODES)
                Yout[(size_t)row * COUT + nt * 16 + m] = f2fp8(acc[nt][r]);
        }
    }
    #pragma unroll
    for (int r = 0; r < 4; r++) {
        int row = rbase + wid * 16 + quad * 4 + r;
        if (row >= N_NODES) continue;
        float v = acc[NTO][r];
        if constexpr (NTO == 8) {
            if (m < 8) als_out[row * 8 + m] = v;
            else       ald_out[row * 8 + (m - 8)] = v;
        } else {
            if (m == 0) als_out[row] = v;
            else if (m == 1) ald_out[row] = v;
        }
    }
}

// ---------------- agg32 + fused mean pool (final layer) ---------------------

__global__ __launch_bounds__(256) void agg32(const u8* __restrict__ Hb,
        const float* __restrict__ als, const float* __restrict__ ald,
        const int* __restrict__ deg, const int* __restrict__ srclist,
        const float* __restrict__ bias, float* __restrict__ outp) {
    __shared__ float lds[4][32];
    int t    = threadIdx.x;
    int wid  = t >> 6;
    int lane = t & 63;
    int sub  = lane >> 3;
    int li   = lane & 7;
    int d    = blockIdx.x * 32 + wid * 8 + sub;   // exact
    int c0 = li * 4;
    float adv = ald[d];
    const int* sl = srclist + (size_t)d * SL_STRIDE;
    int cnt[8];
    *(i32x4*)&cnt[0] = *(const i32x4*)&deg[d * NR];
    *(i32x4*)&cnt[4] = *(const i32x4*)&deg[d * NR + 4];
    float a0=0.f,a1=0.f,a2=0.f,a3=0.f,den=0.f;
    for (int r = 0; r < NR; ++r) {
        int n = cnt[r]; n = n < CAP_R ? n : CAP_R;
        const int* slr = sl + r * CAP_R;
        int j = 0;
        for (; j + 2 <= n; j += 2) {
            int s0 = slr[j], s1 = slr[j+1];
            unsigned u0 = *(const unsigned*)(Hb + (size_t)s0 * 32 + c0);
            unsigned u1 = *(const unsigned*)(Hb + (size_t)s1 * 32 + c0);
            float x0 = als[s0], x1 = als[s1];
            float l0 = x0 + adv; l0 = fmaxf(l0, NEG*l0); float w0 = __expf(l0);
            float l1 = x1 + adv; l1 = fmaxf(l1, NEG*l1); float w1 = __expf(l1);
            den += w0 + w1;
            f32x2 p;
            p = __builtin_amdgcn_cvt_pk_f32_fp8((int)u0, false); a0=fmaf(w0,p[0],a0); a1=fmaf(w0,p[1],a1);
            p = __builtin_amdgcn_cvt_pk_f32_fp8((int)u0, true);  a2=fmaf(w0,p[0],a2); a3=fmaf(w0,p[1],a3);
            p = __builtin_amdgcn_cvt_pk_f32_fp8((int)u1, false); a0=fmaf(w1,p[0],a0); a1=fmaf(w1,p[1],a1);
            p = __builtin_amdgcn_cvt_pk_f32_fp8((int)u1, true);  a2=fmaf(w1,p[0],a2); a3=fmaf(w1,p[1],a3);
        }
        if (j < n) {
            int s0 = slr[j];
            unsigned u0 = *(const unsigned*)(Hb + (size_t)s0 * 32 + c0);
            float x0 = als[s0];
            float l0 = x0 + adv; l0 = fmaxf(l0, NEG*l0); float w0 = __expf(l0);
            den += w0;
            f32x2 p;
            p = __builtin_amdgcn_cvt_pk_f32_fp8((int)u0, false); a0=fmaf(w0,p[0],a0); a1=fmaf(w0,p[1],a1);
            p = __builtin_amdgcn_cvt_pk_f32_fp8((int)u0, true);  a2=fmaf(w0,p[0],a2); a3=fmaf(w0,p[1],a3);
        }
    }
    float r = 1.f / den;
    float4 bv = *(const float4*)&bias[c0];
    float o0 = fmaf(a0, r, bv.x), o1 = fmaf(a1, r, bv.y);
    float o2 = fmaf(a2, r, bv.z), o3 = fmaf(a3, r, bv.w);
    #pragma unroll
    for (int mask = 8; mask < 64; mask <<= 1) {
        o0 += __shfl_xor(o0, mask);
        o1 += __shfl_xor(o1, mask);
        o2 += __shfl_xor(o2, mask);
        o3 += __shfl_xor(o3, mask);
    }
    if (sub == 0) {
        lds[wid][c0]     = o0;
        lds[wid][c0 + 1] = o1;
        lds[wid][c0 + 2] = o2;
        lds[wid][c0 + 3] = o3;
    }
    __syncthreads();
    if (t < 32)
        atomicAdd(&outp[t],
            (lds[0][t] + lds[1][t] + lds[2][t] + lds[3][t]) * (1.0f / N_NODES));
}

// ---------------- launch ----------------

extern "C" void kernel_launch(void* const* d_in, const int* in_sizes, int n_in,
                              void* d_out, int out_size, void* d_ws, size_t ws_size,
                              hipStream_t stream) {
    (void)in_sizes; (void)n_in; (void)out_size; (void)ws_size;
    const float* x   = (const float*)d_in[0];
    const int*   ei  = (const int*)d_in[1];
    const float* W1  = (const float*)d_in[2];
    const float* as1 = (const float*)d_in[3];
    const float* ad1 = (const float*)d_in[4];
    const float* b1  = (const float*)d_in[5];
    const float* W2  = (const float*)d_in[6];
    const float* as2 = (const float*)d_in[7];
    const float* ad2 = (const float*)d_in[8];
    const float* b2  = (const float*)d_in[9];
    const float* W3  = (const float*)d_in[10];
    const float* as3 = (const float*)d_in[11];
    const float* ad3 = (const float*)d_in[12];
    const float* b3  = (const float*)d_in[13];

    char* ws = (char*)d_ws;
    size_t off = 0;
    auto carve = [&](size_t bytes) { void* p = ws + off; off += (bytes + 255) & ~size_t(255); return p; };
    u8*    bufHa   = (u8*)carve(size_t(N_NODES) * 128);        // L1 feat fp8; reused for L3 feat (32B rows)
    u8*    bufHb   = (u8*)carve(size_t(N_NODES) * 128);        // L2 feat fp8
    float* alsA    = (float*)carve(size_t(N_NODES) * 8 * 4);   // L1 logits; reused for L3
    float* aldA    = (float*)carve(size_t(N_NODES) * 8 * 4);
    float* alsB    = (float*)carve(size_t(N_NODES) * 8 * 4);   // L2 logits
    float* aldB    = (float*)carve(size_t(N_NODES) * 8 * 4);
    int*   cursor  = (int*)carve(size_t(N_NODES) * NR * 4);    // per-(dst,range)
    bfu*   WtX1    = (bfu*)carve(144 * 128 * 2);
    bfu*   WtX2    = (bfu*)carve(144 * 128 * 2);
    bfu*   WtX3    = (bfu*)carve(48 * 128 * 2);
    int*   srclist = (int*)carve(size_t(N_NODES) * SL_STRIDE * 4);  // 44.8 MB

    // prep (WtX*) + cursor zero + d_out zero -- one tiny dispatch
    prep_cursor<<<PREP_B, 256, 0, stream>>>(W1, W2, W3,
        as1, ad1, as2, ad2, as3, ad3, WtX1, WtX2, WtX3, cursor, (float*)d_out);

    // CSR bucket fill (src-range bucketed)
    fill<<<FILL_B, 256, 0, stream>>>(ei, cursor, srclist);

    // layer 1 gemm (x f32 -> bufHa fp8 + logits A)
    gemm_mfma_l1<<<GEMM_B, 256, 0, stream>>>(x, WtX1, bufHa, alsA, aldA);

    // layer 2: fused agg(L1) + gemm2 (reads bufHa, writes bufHb + logits B)
    fused_agg_gemm<8><<<FUSE_B, 256, 0, stream>>>(bufHa, alsA, aldA,
        cursor, srclist, b1, WtX2, bufHb, alsB, aldB);

    // layer 3: fused agg(L2) + gemm3 (reads bufHb, writes bufHa(32B rows) + logits A)
    fused_agg_gemm<2><<<FUSE_B, 256, 0, stream>>>(bufHb, alsB, aldB,
        cursor, srclist, b2, WtX3, bufHa, alsA, aldA);

    // final aggregation + mean pool
    agg32<<<AGG32_B, 256, 0, stream>>>(bufHa, alsA, aldA, cursor, srclist, b3, (float*)d_out);
}

// Round 6
// 412.065 us; speedup vs baseline: 1.2042x; 1.2042x over previous
//
#include <hip/hip_runtime.h>

// GAT (3-layer) on MI355X.
// R18: revert R17's src-range bucketing entirely (pre-registered FETCH signal
//      failed: 152.9MB unchanged, dur +26us from range-loop divergence --
//      phase alignment doesn't survive block drift without grid barriers).
//      New lever from R16/R17 counters: fused OccupancyPercent 25-32% with
//      6.1 blocks/CU AVAILABLE = drain-tail-bound (most wall time has ~2
//      blocks/CU alive; 64-dst blocks are too coarse to backfill).
//      -> fused blocks go 256thr/64dst -> 128thr/32dst (3125 blocks,
//      12.2/CU): finer granularity, scheduler backfills, tail shrinks.
//      Prediction: fused 91->60-75us + occ>45% if tail-bound; flat if
//      fabric-bound (FETCH ~154MB either way).
//      Kept: R15 agg+gemm LDS fusion, CAP=48 flat srclist, pipelined fill,
//      prep_cursor fold, ping-pong buffers.

typedef unsigned short bfu;
typedef unsigned char u8;
typedef __attribute__((ext_vector_type(8))) short bf16x8;
typedef __attribute__((ext_vector_type(4))) float f32x4;
typedef __attribute__((ext_vector_type(2))) float f32x2;
typedef __attribute__((ext_vector_type(4))) int i32x4;

constexpr int N_NODES = 100000;
constexpr int E_IN    = 1600000;
constexpr int E_TOT   = E_IN + N_NODES;   // + self loops
constexpr float NEG   = 0.2f;
constexpr int P_XCD   = 8;
constexpr int PSZ     = N_NODES / P_XCD;  // 12500
constexpr int CAP     = 48;               // bucket slots/node (max deg ~39)
constexpr int AGG32_B = N_NODES / 32;     // 3125
constexpr int GEMM_B  = (N_NODES + 63) / 64;        // 1563
constexpr int FUSE_B  = N_NODES / 32;               // 3125 (32 dst rows/block)
constexpr int EDGE_B4 = (E_TOT / 4 + 255) / 256;    // 1661
constexpr int FILL_B  = EDGE_B4 * P_XCD;            // 13288
constexpr int PREP_ITEMS = 43008;
constexpr int PREP_B  = (PREP_ITEMS + 255) / 256;   // 168

__device__ inline bfu f2bf(float f) {
    union { float f; unsigned i; } c; c.f = f;
    unsigned x = c.i;
    return (bfu)((x + 0x7fffu + ((x >> 16) & 1u)) >> 16);
}
__device__ inline u8 f2fp8(float f) {
    return (u8)(__builtin_amdgcn_cvt_pk_fp8_f32(f, f, 0, false) & 0xff);
}

// ---------------- prep: W^T + folded logit columns (bf16) -------------------
// WtX1/WtX2: 144 rows x 128 k  (rows 0-127 = W^T; 128-135 = ws; 136-143 = wd)
// WtX3:      48 rows x 128 k   (rows 0-31 = W3^T; 32 = ws3; 33 = wd3; 34-47 = 0)

__device__ inline void prep_body(int idx,
        const float* __restrict__ W1, const float* __restrict__ W2,
        const float* __restrict__ W3,
        const float* __restrict__ as1, const float* __restrict__ ad1,
        const float* __restrict__ as2, const float* __restrict__ ad2,
        const float* __restrict__ as3, const float* __restrict__ ad3,
        bfu* __restrict__ WtX1, bfu* __restrict__ WtX2, bfu* __restrict__ WtX3) {
    if (idx < 16384) {
        int k = idx >> 7, n = idx & 127;
        WtX1[n * 128 + k] = f2bf(W1[idx]);
    } else if (idx < 32768) {
        int r = idx - 16384;
        int k = r >> 7, n = r & 127;
        WtX2[n * 128 + k] = f2bf(W2[r]);
    } else if (idx < 36864) {
        int r = idx - 32768;
        int k = r >> 5, n = r & 31;
        WtX3[n * 128 + k] = f2bf(W3[r]);
    } else if (idx < 38912) {          // layer-1 ws/wd: 2 x 8h x 128k
        int r = idx - 36864;
        int sd = r >> 10, rr = r & 1023;
        int h = rr >> 7, k = rr & 127;
        const float* a = sd ? ad1 : as1;
        float v = 0.f;
        #pragma unroll
        for (int c = 0; c < 16; ++c) v += W1[k * 128 + h * 16 + c] * a[h * 16 + c];
        WtX1[(128 + sd * 8 + h) * 128 + k] = f2bf(v);
    } else if (idx < 40960) {          // layer-2 ws/wd
        int r = idx - 38912;
        int sd = r >> 10, rr = r & 1023;
        int h = rr >> 7, k = rr & 127;
        const float* a = sd ? ad2 : as2;
        float v = 0.f;
        #pragma unroll
        for (int c = 0; c < 16; ++c) v += W2[k * 128 + h * 16 + c] * a[h * 16 + c];
        WtX2[(128 + sd * 8 + h) * 128 + k] = f2bf(v);
    } else if (idx < 41216) {          // layer-3 ws/wd: 2 x 128k
        int r = idx - 40960;
        int sd = r >> 7, k = r & 127;
        const float* a = sd ? ad3 : as3;
        float v = 0.f;
        #pragma unroll
        for (int c = 0; c < 32; ++c) v += W3[k * 32 + c] * a[c];
        WtX3[(32 + sd) * 128 + k] = f2bf(v);
    } else if (idx < 43008) {          // zero rows 34-47 of WtX3
        WtX3[34 * 128 + (idx - 41216)] = 0;
    }
}

// prep + cursor-zero + out-zero in one tiny dispatch (replaces 2 memsets).
__global__ __launch_bounds__(256) void prep_cursor(
        const float* __restrict__ W1, const float* __restrict__ W2,
        const float* __restrict__ W3,
        const float* __restrict__ as1, const float* __restrict__ ad1,
        const float* __restrict__ as2, const float* __restrict__ ad2,
        const float* __restrict__ as3, const float* __restrict__ ad3,
        bfu* __restrict__ WtX1, bfu* __restrict__ WtX2, bfu* __restrict__ WtX3,
        int* __restrict__ cursor, float* __restrict__ outp) {
    int idx = blockIdx.x * 256 + threadIdx.x;
    prep_body(idx, W1, W2, W3, as1, ad1, as2, ad2, as3, ad3, WtX1, WtX2, WtX3);
    for (int i = idx; i < N_NODES; i += PREP_ITEMS) cursor[i] = 0;
    if (idx < 32) outp[idx] = 0.f;
}

// ---------------- fill (dst-partitioned, atomic chains pipelined) -----------

__global__ __launch_bounds__(256) void fill(const int* __restrict__ ei,
        int* __restrict__ cursor, int* __restrict__ srclist) {
    int p = blockIdx.x & 7;
    int b = blockIdx.x >> 3;
    int lo = p * PSZ, hi = lo + PSZ;
    int e0 = (b * 256 + threadIdx.x) * 4;
    if (e0 >= E_TOT) return;
    bool self = e0 >= E_IN;
    i32x4 d4, s4;
    if (!self) {
        d4 = __builtin_nontemporal_load((const i32x4*)&ei[E_IN + e0]);
        s4 = __builtin_nontemporal_load((const i32x4*)&ei[e0]);
    } else {
        int bb = e0 - E_IN;
        d4[0] = bb; d4[1] = bb + 1; d4[2] = bb + 2; d4[3] = bb + 3;
        s4 = d4;
    }
    int pos[4];
    #pragma unroll
    for (int q = 0; q < 4; ++q) {
        int d = d4[q];
        pos[q] = (d >= lo && d < hi) ? atomicAdd(&cursor[d], 1) : -1;
    }
    #pragma unroll
    for (int q = 0; q < 4; ++q) {
        if (pos[q] >= 0 && pos[q] < CAP)
            srclist[d4[q] * CAP + pos[q]] = s4[q];
    }
}

// ---------------- MFMA GEMM (layer 1 only), logits as extra B-tile ----------
// C/D layout: row = quad*4+r, col = nt*16+m.

__device__ inline bf16x8 ldcvt_f32(const float* p) {
    float4 v0 = *(const float4*)p;
    float4 v1 = *(const float4*)(p + 4);
    bf16x8 a;
    a[0] = (short)f2bf(v0.x); a[1] = (short)f2bf(v0.y);
    a[2] = (short)f2bf(v0.z); a[3] = (short)f2bf(v0.w);
    a[4] = (short)f2bf(v1.x); a[5] = (short)f2bf(v1.y);
    a[6] = (short)f2bf(v1.z); a[7] = (short)f2bf(v1.w);
    return a;
}

__global__ __launch_bounds__(256) void gemm_mfma_l1(const float* __restrict__ Xg,
                                                    const bfu* __restrict__ Wt,
                                                    u8* __restrict__ Y,
                                                    float* __restrict__ als,
                                                    float* __restrict__ ald) {
    constexpr int NTO = 8;
    constexpr int COUT = 128;
    int wid  = threadIdx.x >> 6;
    int lane = threadIdx.x & 63;
    int m = lane & 15, quad = lane >> 4;
    int rbase = (blockIdx.x * 4 + wid) * 16;
    if (rbase >= N_NODES) return;
    int rA = rbase + m; if (rA >= N_NODES) rA = N_NODES - 1;

    const float* Ap = Xg + (size_t)rA * 128 + quad * 8;
    bf16x8 a0 = ldcvt_f32(Ap);
    bf16x8 a1 = ldcvt_f32(Ap + 32);
    bf16x8 a2 = ldcvt_f32(Ap + 64);
    bf16x8 a3 = ldcvt_f32(Ap + 96);

    const bfu* Bp = Wt + (size_t)m * 128 + quad * 8;
    f32x4 acc[NTO + 1];
    #pragma unroll
    for (int nt = 0; nt <= NTO; nt++) {
        const bfu* Bn = Bp + nt * 16 * 128;
        f32x4 c = {0.f, 0.f, 0.f, 0.f};
        c = __builtin_amdgcn_mfma_f32_16x16x32_bf16(a0, *(const bf16x8*)(Bn),      c, 0, 0, 0);
        c = __builtin_amdgcn_mfma_f32_16x16x32_bf16(a1, *(const bf16x8*)(Bn + 32), c, 0, 0, 0);
        c = __builtin_amdgcn_mfma_f32_16x16x32_bf16(a2, *(const bf16x8*)(Bn + 64), c, 0, 0, 0);
        c = __builtin_amdgcn_mfma_f32_16x16x32_bf16(a3, *(const bf16x8*)(Bn + 96), c, 0, 0, 0);
        acc[nt] = c;
    }

    #pragma unroll
    for (int nt = 0; nt < NTO; nt++) {
        #pragma unroll
        for (int r = 0; r < 4; r++) {
            int row = rbase + quad * 4 + r;
            if (row < N_NODES)
                Y[(size_t)row * COUT + nt * 16 + m] = f2fp8(acc[nt][r]);
        }
    }
    #pragma unroll
    for (int r = 0; r < 4; r++) {
        int row = rbase + quad * 4 + r;
        if (row >= N_NODES) continue;
        float v = acc[NTO][r];
        if (m < 8) als[row * 8 + m] = v;
        else       ald[row * 8 + (m - 8)] = v;
    }
}

// ---------------- fused agg + gemm ------------------------------------------
// 128 threads / 32 dst rows per block (R18: fine-grained for tail backfill).
// Phase 1 (agg): 2 waves x 8 dst x 2 iters = 32 dst rows -> bf16 in LDS.
//   Gather loop unrolled 4-wide (8 outstanding loads/lane).
//   LDS: 32 rows x 16 granules(16B), swizzled gran ^= (row&7) both sides.
// Phase 2 (gemm): 32-row MFMA tile (2 waves x 16 rows), A from LDS.

__device__ inline void unpack_fma(uint4 u, float w, float* a) {
    f32x2 p;
    p = __builtin_amdgcn_cvt_pk_f32_fp8((int)u.x, false); a[0]=fmaf(w,p[0],a[0]);  a[1]=fmaf(w,p[1],a[1]);
    p = __builtin_amdgcn_cvt_pk_f32_fp8((int)u.x, true);  a[2]=fmaf(w,p[0],a[2]);  a[3]=fmaf(w,p[1],a[3]);
    p = __builtin_amdgcn_cvt_pk_f32_fp8((int)u.y, false); a[4]=fmaf(w,p[0],a[4]);  a[5]=fmaf(w,p[1],a[5]);
    p = __builtin_amdgcn_cvt_pk_f32_fp8((int)u.y, true);  a[6]=fmaf(w,p[0],a[6]);  a[7]=fmaf(w,p[1],a[7]);
    p = __builtin_amdgcn_cvt_pk_f32_fp8((int)u.z, false); a[8]=fmaf(w,p[0],a[8]);  a[9]=fmaf(w,p[1],a[9]);
    p = __builtin_amdgcn_cvt_pk_f32_fp8((int)u.z, true);  a[10]=fmaf(w,p[0],a[10]); a[11]=fmaf(w,p[1],a[11]);
    p = __builtin_amdgcn_cvt_pk_f32_fp8((int)u.w, false); a[12]=fmaf(w,p[0],a[12]); a[13]=fmaf(w,p[1],a[13]);
    p = __builtin_amdgcn_cvt_pk_f32_fp8((int)u.w, true);  a[14]=fmaf(w,p[0],a[14]); a[15]=fmaf(w,p[1],a[15]);
}

template<int NTO>
__global__ __launch_bounds__(128) void fused_agg_gemm(
        const u8* __restrict__ Hin,       // N x 128 fp8 (prev gemm out)
        const float* __restrict__ als_in, // N x 8
        const float* __restrict__ ald_in, // N x 8
        const int* __restrict__ deg, const int* __restrict__ srclist,
        const float* __restrict__ bias,   // 128 (prev layer bias)
        const bfu* __restrict__ Wt,       // (NTO+1)*16 x 128 bf16
        u8* __restrict__ Yout,            // N x NTO*16 fp8
        float* __restrict__ als_out, float* __restrict__ ald_out) {
    __shared__ uint4 ldsb[32 * 16];       // 8 KB
    int t    = threadIdx.x;
    int wid  = t >> 6;                    // 0..1
    int lane = t & 63;
    int sub  = lane >> 3;
    int li   = lane & 7;
    int rbase = blockIdx.x * 32;

    // ---- phase 1: aggregate 32 dst nodes into LDS ----
    #pragma unroll
    for (int it = 0; it < 2; ++it) {
        int dl = wid * 16 + it * 8 + sub;          // 0..31
        int d  = rbase + dl;                       // exact: N % 32 == 0
        {
            int c0 = li * 16;
            float ad = ald_in[d * 8 + li];
            const int* sl = srclist + d * CAP;
            int n = deg[d]; n = n < CAP ? n : CAP;
            float a[16];
            #pragma unroll
            for (int k = 0; k < 16; ++k) a[k] = 0.f;
            float den = 0.f;
            int j = 0;
            for (; j + 4 <= n; j += 4) {
                int s0 = sl[j], s1 = sl[j+1], s2 = sl[j+2], s3 = sl[j+3];
                uint4 u0 = *(const uint4*)(Hin + (size_t)s0 * 128 + c0);
                uint4 u1 = *(const uint4*)(Hin + (size_t)s1 * 128 + c0);
                uint4 u2 = *(const uint4*)(Hin + (size_t)s2 * 128 + c0);
                uint4 u3 = *(const uint4*)(Hin + (size_t)s3 * 128 + c0);
                float x0 = als_in[s0 * 8 + li], x1 = als_in[s1 * 8 + li];
                float x2 = als_in[s2 * 8 + li], x3 = als_in[s3 * 8 + li];
                float l0 = x0 + ad; l0 = fmaxf(l0, NEG * l0); float w0 = __expf(l0);
                float l1 = x1 + ad; l1 = fmaxf(l1, NEG * l1); float w1 = __expf(l1);
                float l2 = x2 + ad; l2 = fmaxf(l2, NEG * l2); float w2 = __expf(l2);
                float l3 = x3 + ad; l3 = fmaxf(l3, NEG * l3); float w3 = __expf(l3);
                den += (w0 + w1) + (w2 + w3);
                unpack_fma(u0, w0, a);
                unpack_fma(u1, w1, a);
                unpack_fma(u2, w2, a);
                unpack_fma(u3, w3, a);
            }
            if (j + 2 <= n) {
                int s0 = sl[j], s1 = sl[j + 1];
                uint4 u0 = *(const uint4*)(Hin + (size_t)s0 * 128 + c0);
                uint4 u1 = *(const uint4*)(Hin + (size_t)s1 * 128 + c0);
                float x0 = als_in[s0 * 8 + li], x1 = als_in[s1 * 8 + li];
                float l0 = x0 + ad; l0 = fmaxf(l0, NEG * l0); float w0 = __expf(l0);
                float l1 = x1 + ad; l1 = fmaxf(l1, NEG * l1); float w1 = __expf(l1);
                den += w0 + w1;
                unpack_fma(u0, w0, a);
                unpack_fma(u1, w1, a);
                j += 2;
            }
            if (j < n) {
                int s0 = sl[j];
                uint4 u0 = *(const uint4*)(Hin + (size_t)s0 * 128 + c0);
                float x0 = als_in[s0 * 8 + li];
                float l0 = x0 + ad; l0 = fmaxf(l0, NEG * l0); float w0 = __expf(l0);
                den += w0;
                unpack_fma(u0, w0, a);
            }
            float r = 1.f / den;
            unsigned dw[8];
            #pragma unroll
            for (int k = 0; k < 8; ++k) {
                float e0 = fmaxf(fmaf(a[2*k],   r, bias[c0 + 2*k]),   0.f);
                float e1 = fmaxf(fmaf(a[2*k+1], r, bias[c0 + 2*k+1]), 0.f);
                dw[k] = (unsigned)f2bf(e0) | ((unsigned)f2bf(e1) << 16);
            }
            uint4 st0 = {dw[0], dw[1], dw[2], dw[3]};
            uint4 st1 = {dw[4], dw[5], dw[6], dw[7]};
            int sw = dl & 7;
            ldsb[dl * 16 + ((li * 2)     ^ sw)] = st0;
            ldsb[dl * 16 + ((li * 2 + 1) ^ sw)] = st1;
        }
    }
    __syncthreads();

    // ---- phase 2: 32-row MFMA gemm, A from LDS ----
    constexpr int COUT = NTO * 16;
    int m = lane & 15, quad = lane >> 4;
    int lr = wid * 16 + m;
    int lb = lr * 16, sw = lr & 7;
    bf16x8 a0 = *(const bf16x8*)&ldsb[lb + ((quad)      ^ sw)];
    bf16x8 a1 = *(const bf16x8*)&ldsb[lb + ((quad + 4)  ^ sw)];
    bf16x8 a2 = *(const bf16x8*)&ldsb[lb + ((quad + 8)  ^ sw)];
    bf16x8 a3 = *(const bf16x8*)&ldsb[lb + ((quad + 12) ^ sw)];

    const bfu* Bp = Wt + (size_t)m * 128 + quad * 8;
    f32x4 acc[NTO + 1];
    #pragma unroll
    for (int nt = 0; nt <= NTO; nt++) {
        const bfu* Bn = Bp + nt * 16 * 128;
        f32x4 c = {0.f, 0.f, 0.f, 0.f};
        c = __builtin_amdgcn_mfma_f32_16x16x32_bf16(a0, *(const bf16x8*)(Bn),      c, 0, 0, 0);
        c = __builtin_amdgcn_mfma_f32_16x16x32_bf16(a1, *(const bf16x8*)(Bn + 32), c, 0, 0, 0);
        c = __builtin_amdgcn_mfma_f32_16x16x32_bf16(a2, *(const bf16x8*)(Bn + 64), c, 0, 0, 0);
        c = __builtin_amdgcn_mfma_f32_16x16x32_bf16(a3, *(const bf16x8*)(Bn + 96), c, 0, 0, 0);
        acc[nt] = c;
    }

    #pragma unroll
    for (int nt = 0; nt < NTO; nt++) {
        #pragma unroll
        for (int r = 0; r < 4; r++) {
            int row = rbase + wid * 16 + quad * 4 + r;
            Yout[(size_t)row * COUT + nt * 16 + m] = f2fp8(acc[nt][r]);
        }
    }
    #pragma unroll
    for (int r = 0; r < 4; r++) {
        int row = rbase + wid * 16 + quad * 4 + r;
        float v = acc[NTO][r];
        if constexpr (NTO == 8) {
            if (m < 8) als_out[row * 8 + m] = v;
            else       ald_out[row * 8 + (m - 8)] = v;
        } else {
            if (m == 0) als_out[row] = v;
            else if (m == 1) ald_out[row] = v;
        }
    }
}

// ---------------- agg32 + fused mean pool (final layer) ---------------------

__global__ __launch_bounds__(256) void agg32(const u8* __restrict__ Hb,
        const float* __restrict__ als, const float* __restrict__ ald,
        const int* __restrict__ deg, const int* __restrict__ srclist,
        const float* __restrict__ bias, float* __restrict__ outp) {
    __shared__ float lds[4][32];
    int t    = threadIdx.x;
    int wid  = t >> 6;
    int lane = t & 63;
    int sub  = lane >> 3;
    int li   = lane & 7;
    int d    = blockIdx.x * 32 + wid * 8 + sub;   // exact
    int c0 = li * 4;
    float adv = ald[d];
    const int* sl = srclist + d * CAP;
    int n = deg[d]; n = n < CAP ? n : CAP;
    float a0=0.f,a1=0.f,a2=0.f,a3=0.f,den=0.f;
    int j = 0;
    for (; j + 4 <= n; j += 4) {
        int s0 = sl[j], s1 = sl[j+1], s2 = sl[j+2], s3 = sl[j+3];
        unsigned u0 = *(const unsigned*)(Hb + (size_t)s0 * 32 + c0);
        unsigned u1 = *(const unsigned*)(Hb + (size_t)s1 * 32 + c0);
        unsigned u2 = *(const unsigned*)(Hb + (size_t)s2 * 32 + c0);
        unsigned u3 = *(const unsigned*)(Hb + (size_t)s3 * 32 + c0);
        float x0 = als[s0], x1 = als[s1], x2 = als[s2], x3 = als[s3];
        float l0 = x0 + adv; l0 = fmaxf(l0, NEG*l0); float w0 = __expf(l0);
        float l1 = x1 + adv; l1 = fmaxf(l1, NEG*l1); float w1 = __expf(l1);
        float l2 = x2 + adv; l2 = fmaxf(l2, NEG*l2); float w2 = __expf(l2);
        float l3 = x3 + adv; l3 = fmaxf(l3, NEG*l3); float w3 = __expf(l3);
        den += (w0 + w1) + (w2 + w3);
        f32x2 p;
        p = __builtin_amdgcn_cvt_pk_f32_fp8((int)u0, false); a0=fmaf(w0,p[0],a0); a1=fmaf(w0,p[1],a1);
        p = __builtin_amdgcn_cvt_pk_f32_fp8((int)u0, true);  a2=fmaf(w0,p[0],a2); a3=fmaf(w0,p[1],a3);
        p = __builtin_amdgcn_cvt_pk_f32_fp8((int)u1, false); a0=fmaf(w1,p[0],a0); a1=fmaf(w1,p[1],a1);
        p = __builtin_amdgcn_cvt_pk_f32_fp8((int)u1, true);  a2=fmaf(w1,p[0],a2); a3=fmaf(w1,p[1],a3);
        p = __builtin_amdgcn_cvt_pk_f32_fp8((int)u2, false); a0=fmaf(w2,p[0],a0); a1=fmaf(w2,p[1],a1);
        p = __builtin_amdgcn_cvt_pk_f32_fp8((int)u2, true);  a2=fmaf(w2,p[0],a2); a3=fmaf(w2,p[1],a3);
        p = __builtin_amdgcn_cvt_pk_f32_fp8((int)u3, false); a0=fmaf(w3,p[0],a0); a1=fmaf(w3,p[1],a1);
        p = __builtin_amdgcn_cvt_pk_f32_fp8((int)u3, true);  a2=fmaf(w3,p[0],a2); a3=fmaf(w3,p[1],a3);
    }
    for (; j < n; ++j) {
        int s0 = sl[j];
        unsigned u0 = *(const unsigned*)(Hb + (size_t)s0 * 32 + c0);
        float x0 = als[s0];
        float l0 = x0 + adv; l0 = fmaxf(l0, NEG*l0); float w0 = __expf(l0);
        den += w0;
        f32x2 p;
        p = __builtin_amdgcn_cvt_pk_f32_fp8((int)u0, false); a0=fmaf(w0,p[0],a0); a1=fmaf(w0,p[1],a1);
        p = __builtin_amdgcn_cvt_pk_f32_fp8((int)u0, true);  a2=fmaf(w0,p[0],a2); a3=fmaf(w0,p[1],a3);
    }
    float r = 1.f / den;
    float4 bv = *(const float4*)&bias[c0];
    float o0 = fmaf(a0, r, bv.x), o1 = fmaf(a1, r, bv.y);
    float o2 = fmaf(a2, r, bv.z), o3 = fmaf(a3, r, bv.w);
    #pragma unroll
    for (int mask = 8; mask < 64; mask <<= 1) {
        o0 += __shfl_xor(o0, mask);
        o1 += __shfl_xor(o1, mask);
        o2 += __shfl_xor(o2, mask);
        o3 += __shfl_xor(o3, mask);
    }
    if (sub == 0) {
        lds[wid][c0]     = o0;
        lds[wid][c0 + 1] = o1;
        lds[wid][c0 + 2] = o2;
        lds[wid][c0 + 3] = o3;
    }
    __syncthreads();
    if (t < 32)
        atomicAdd(&outp[t],
            (lds[0][t] + lds[1][t] + lds[2][t] + lds[3][t]) * (1.0f / N_NODES));
}

// ---------------- launch ----------------

extern "C" void kernel_launch(void* const* d_in, const int* in_sizes, int n_in,
                              void* d_out, int out_size, void* d_ws, size_t ws_size,
                              hipStream_t stream) {
    (void)in_sizes; (void)n_in; (void)out_size; (void)ws_size;
    const float* x   = (const float*)d_in[0];
    const int*   ei  = (const int*)d_in[1];
    const float* W1  = (const float*)d_in[2];
    const float* as1 = (const float*)d_in[3];
    const float* ad1 = (const float*)d_in[4];
    const float* b1  = (const float*)d_in[5];
    const float* W2  = (const float*)d_in[6];
    const float* as2 = (const float*)d_in[7];
    const float* ad2 = (const float*)d_in[8];
    const float* b2  = (const float*)d_in[9];
    const float* W3  = (const float*)d_in[10];
    const float* as3 = (const float*)d_in[11];
    const float* ad3 = (const float*)d_in[12];
    const float* b3  = (const float*)d_in[13];

    char* ws = (char*)d_ws;
    size_t off = 0;
    auto carve = [&](size_t bytes) { void* p = ws + off; off += (bytes + 255) & ~size_t(255); return p; };
    u8*    bufHa   = (u8*)carve(size_t(N_NODES) * 128);        // L1 feat fp8; reused for L3 feat (32B rows)
    u8*    bufHb   = (u8*)carve(size_t(N_NODES) * 128);        // L2 feat fp8
    float* alsA    = (float*)carve(size_t(N_NODES) * 8 * 4);   // L1 logits; reused for L3
    float* aldA    = (float*)carve(size_t(N_NODES) * 8 * 4);
    float* alsB    = (float*)carve(size_t(N_NODES) * 8 * 4);   // L2 logits
    float* aldB    = (float*)carve(size_t(N_NODES) * 8 * 4);
    int*   cursor  = (int*)carve(size_t(N_NODES) * 4);
    bfu*   WtX1    = (bfu*)carve(144 * 128 * 2);
    bfu*   WtX2    = (bfu*)carve(144 * 128 * 2);
    bfu*   WtX3    = (bfu*)carve(48 * 128 * 2);
    int*   srclist = (int*)carve(size_t(N_NODES) * CAP * 4);

    // prep (WtX*) + cursor zero + d_out zero -- one tiny dispatch
    prep_cursor<<<PREP_B, 256, 0, stream>>>(W1, W2, W3,
        as1, ad1, as2, ad2, as3, ad3, WtX1, WtX2, WtX3, cursor, (float*)d_out);

    // CSR bucket fill
    fill<<<FILL_B, 256, 0, stream>>>(ei, cursor, srclist);

    // layer 1 gemm (x f32 -> bufHa fp8 + logits A)
    gemm_mfma_l1<<<GEMM_B, 256, 0, stream>>>(x, WtX1, bufHa, alsA, aldA);

    // layer 2: fused agg(L1) + gemm2 (reads bufHa, writes bufHb + logits B)
    fused_agg_gemm<8><<<FUSE_B, 128, 0, stream>>>(bufHa, alsA, aldA,
        cursor, srclist, b1, WtX2, bufHb, alsB, aldB);

    // layer 3: fused agg(L2) + gemm3 (reads bufHb, writes bufHa(32B rows) + logits A)
    fused_agg_gemm<2><<<FUSE_B, 128, 0, stream>>>(bufHb, alsB, aldB,
        cursor, srclist, b2, WtX3, bufHa, alsA, aldA);

    // final aggregation + mean pool
    agg32<<<AGG32_B, 256, 0, stream>>>(bufHa, alsA, aldA, cursor, srclist, b3, (float*)d_out);
}

// Round 7
// 401.492 us; speedup vs baseline: 1.2360x; 1.0263x over previous
//
#include <hip/hip_runtime.h>

// GAT (3-layer) on MI355X.
// R19: fused<8>/<2> declared structurally floored: compulsory fabric traffic
//      (8x Hin replication 102MB + als 26MB + srclist 13MB ~= 144MB) matches
//      measured 156MB; ~2TB/s random-fabric rate confirmed by three nulls
//      (R16 MLP, R17 phasing, R18 granularity). 86us each ~= floor+tail.
//      This round: reclaim gemm1's ~30us of solo runtime by merging it into
//      the fill dispatch, GEMM-BLOCKS-FIRST (R13's failure was fill-majority
//      interleaving: gemm resident throughout, occ 46%, L2 polluted all
//      dispatch). Here all 1563 gemm blocks fit the initial resident wave
//      (~2048 block capacity), drain in ~25us, fill backfills; pollution
//      window = first third of fill only. GOFF=1568 (==0 mod 8) keeps fill's
//      partition<->XCD alignment identical to R18. Merged VGPR ~60 < 64 ->
//      fill keeps full occupancy headroom. Revert if fill_gemm1 > 100us.
//      Kept: R18 128thr/32dst fused blocks, CAP=48, pipelined fill,
//      prep_cursor fold, ping-pong buffers.

typedef unsigned short bfu;
typedef unsigned char u8;
typedef __attribute__((ext_vector_type(8))) short bf16x8;
typedef __attribute__((ext_vector_type(4))) float f32x4;
typedef __attribute__((ext_vector_type(2))) float f32x2;
typedef __attribute__((ext_vector_type(4))) int i32x4;

constexpr int N_NODES = 100000;
constexpr int E_IN    = 1600000;
constexpr int E_TOT   = E_IN + N_NODES;   // + self loops
constexpr float NEG   = 0.2f;
constexpr int P_XCD   = 8;
constexpr int PSZ     = N_NODES / P_XCD;  // 12500
constexpr int CAP     = 48;               // bucket slots/node (max deg ~39)
constexpr int AGG32_B = N_NODES / 32;     // 3125
constexpr int GEMM_B  = (N_NODES + 63) / 64;        // 1563
constexpr int GOFF    = ((GEMM_B + 7) / 8) * 8;     // 1568 (keep fill%8 alignment)
constexpr int FUSE_B  = N_NODES / 32;               // 3125 (32 dst rows/block)
constexpr int EDGE_B4 = (E_TOT / 4 + 255) / 256;    // 1661
constexpr int FILL_B  = EDGE_B4 * P_XCD;            // 13288
constexpr int FG_GRID = GOFF + FILL_B;              // 14856
constexpr int PREP_ITEMS = 43008;
constexpr int PREP_B  = (PREP_ITEMS + 255) / 256;   // 168

__device__ inline bfu f2bf(float f) {
    union { float f; unsigned i; } c; c.f = f;
    unsigned x = c.i;
    return (bfu)((x + 0x7fffu + ((x >> 16) & 1u)) >> 16);
}
__device__ inline u8 f2fp8(float f) {
    return (u8)(__builtin_amdgcn_cvt_pk_fp8_f32(f, f, 0, false) & 0xff);
}

// ---------------- prep: W^T + folded logit columns (bf16) -------------------
// WtX1/WtX2: 144 rows x 128 k  (rows 0-127 = W^T; 128-135 = ws; 136-143 = wd)
// WtX3:      48 rows x 128 k   (rows 0-31 = W3^T; 32 = ws3; 33 = wd3; 34-47 = 0)

__device__ inline void prep_body(int idx,
        const float* __restrict__ W1, const float* __restrict__ W2,
        const float* __restrict__ W3,
        const float* __restrict__ as1, const float* __restrict__ ad1,
        const float* __restrict__ as2, const float* __restrict__ ad2,
        const float* __restrict__ as3, const float* __restrict__ ad3,
        bfu* __restrict__ WtX1, bfu* __restrict__ WtX2, bfu* __restrict__ WtX3) {
    if (idx < 16384) {
        int k = idx >> 7, n = idx & 127;
        WtX1[n * 128 + k] = f2bf(W1[idx]);
    } else if (idx < 32768) {
        int r = idx - 16384;
        int k = r >> 7, n = r & 127;
        WtX2[n * 128 + k] = f2bf(W2[r]);
    } else if (idx < 36864) {
        int r = idx - 32768;
        int k = r >> 5, n = r & 31;
        WtX3[n * 128 + k] = f2bf(W3[r]);
    } else if (idx < 38912) {          // layer-1 ws/wd: 2 x 8h x 128k
        int r = idx - 36864;
        int sd = r >> 10, rr = r & 1023;
        int h = rr >> 7, k = rr & 127;
        const float* a = sd ? ad1 : as1;
        float v = 0.f;
        #pragma unroll
        for (int c = 0; c < 16; ++c) v += W1[k * 128 + h * 16 + c] * a[h * 16 + c];
        WtX1[(128 + sd * 8 + h) * 128 + k] = f2bf(v);
    } else if (idx < 40960) {          // layer-2 ws/wd
        int r = idx - 38912;
        int sd = r >> 10, rr = r & 1023;
        int h = rr >> 7, k = rr & 127;
        const float* a = sd ? ad2 : as2;
        float v = 0.f;
        #pragma unroll
        for (int c = 0; c < 16; ++c) v += W2[k * 128 + h * 16 + c] * a[h * 16 + c];
        WtX2[(128 + sd * 8 + h) * 128 + k] = f2bf(v);
    } else if (idx < 41216) {          // layer-3 ws/wd: 2 x 128k
        int r = idx - 40960;
        int sd = r >> 7, k = r & 127;
        const float* a = sd ? ad3 : as3;
        float v = 0.f;
        #pragma unroll
        for (int c = 0; c < 32; ++c) v += W3[k * 32 + c] * a[c];
        WtX3[(32 + sd) * 128 + k] = f2bf(v);
    } else if (idx < 43008) {          // zero rows 34-47 of WtX3
        WtX3[34 * 128 + (idx - 41216)] = 0;
    }
}

// prep + cursor-zero + out-zero in one tiny dispatch (replaces 2 memsets).
__global__ __launch_bounds__(256) void prep_cursor(
        const float* __restrict__ W1, const float* __restrict__ W2,
        const float* __restrict__ W3,
        const float* __restrict__ as1, const float* __restrict__ ad1,
        const float* __restrict__ as2, const float* __restrict__ ad2,
        const float* __restrict__ as3, const float* __restrict__ ad3,
        bfu* __restrict__ WtX1, bfu* __restrict__ WtX2, bfu* __restrict__ WtX3,
        int* __restrict__ cursor, float* __restrict__ outp) {
    int idx = blockIdx.x * 256 + threadIdx.x;
    prep_body(idx, W1, W2, W3, as1, ad1, as2, ad2, as3, ad3, WtX1, WtX2, WtX3);
    for (int i = idx; i < N_NODES; i += PREP_ITEMS) cursor[i] = 0;
    if (idx < 32) outp[idx] = 0.f;
}

// ---------------- fill body (dst-partitioned, atomic chains pipelined) ------

__device__ inline void fill_body(int fb, const int* __restrict__ ei,
        int* __restrict__ cursor, int* __restrict__ srclist) {
    int p = fb & 7;
    int b = fb >> 3;
    int lo = p * PSZ, hi = lo + PSZ;
    int e0 = (b * 256 + threadIdx.x) * 4;
    if (e0 >= E_TOT) return;
    bool self = e0 >= E_IN;
    i32x4 d4, s4;
    if (!self) {
        d4 = __builtin_nontemporal_load((const i32x4*)&ei[E_IN + e0]);
        s4 = __builtin_nontemporal_load((const i32x4*)&ei[e0]);
    } else {
        int bb = e0 - E_IN;
        d4[0] = bb; d4[1] = bb + 1; d4[2] = bb + 2; d4[3] = bb + 3;
        s4 = d4;
    }
    int pos[4];
    #pragma unroll
    for (int q = 0; q < 4; ++q) {
        int d = d4[q];
        pos[q] = (d >= lo && d < hi) ? atomicAdd(&cursor[d], 1) : -1;
    }
    #pragma unroll
    for (int q = 0; q < 4; ++q) {
        if (pos[q] >= 0 && pos[q] < CAP)
            srclist[d4[q] * CAP + pos[q]] = s4[q];
    }
}

// ---------------- MFMA GEMM body (layer 1), logits as extra B-tile ----------
// C/D layout: row = quad*4+r, col = nt*16+m.

__device__ inline bf16x8 ldcvt_f32(const float* p) {
    float4 v0 = *(const float4*)p;
    float4 v1 = *(const float4*)(p + 4);
    bf16x8 a;
    a[0] = (short)f2bf(v0.x); a[1] = (short)f2bf(v0.y);
    a[2] = (short)f2bf(v0.z); a[3] = (short)f2bf(v0.w);
    a[4] = (short)f2bf(v1.x); a[5] = (short)f2bf(v1.y);
    a[6] = (short)f2bf(v1.z); a[7] = (short)f2bf(v1.w);
    return a;
}

__device__ inline void gemm1_body(int bid, const float* __restrict__ Xg,
                                  const bfu* __restrict__ Wt,
                                  u8* __restrict__ Y,
                                  float* __restrict__ als,
                                  float* __restrict__ ald) {
    constexpr int NTO = 8;
    constexpr int COUT = 128;
    int wid  = threadIdx.x >> 6;
    int lane = threadIdx.x & 63;
    int m = lane & 15, quad = lane >> 4;
    int rbase = (bid * 4 + wid) * 16;
    if (rbase >= N_NODES) return;
    int rA = rbase + m; if (rA >= N_NODES) rA = N_NODES - 1;

    const float* Ap = Xg + (size_t)rA * 128 + quad * 8;
    bf16x8 a0 = ldcvt_f32(Ap);
    bf16x8 a1 = ldcvt_f32(Ap + 32);
    bf16x8 a2 = ldcvt_f32(Ap + 64);
    bf16x8 a3 = ldcvt_f32(Ap + 96);

    const bfu* Bp = Wt + (size_t)m * 128 + quad * 8;
    f32x4 acc[NTO + 1];
    #pragma unroll
    for (int nt = 0; nt <= NTO; nt++) {
        const bfu* Bn = Bp + nt * 16 * 128;
        f32x4 c = {0.f, 0.f, 0.f, 0.f};
        c = __builtin_amdgcn_mfma_f32_16x16x32_bf16(a0, *(const bf16x8*)(Bn),      c, 0, 0, 0);
        c = __builtin_amdgcn_mfma_f32_16x16x32_bf16(a1, *(const bf16x8*)(Bn + 32), c, 0, 0, 0);
        c = __builtin_amdgcn_mfma_f32_16x16x32_bf16(a2, *(const bf16x8*)(Bn + 64), c, 0, 0, 0);
        c = __builtin_amdgcn_mfma_f32_16x16x32_bf16(a3, *(const bf16x8*)(Bn + 96), c, 0, 0, 0);
        acc[nt] = c;
    }

    #pragma unroll
    for (int nt = 0; nt < NTO; nt++) {
        #pragma unroll
        for (int r = 0; r < 4; r++) {
            int row = rbase + quad * 4 + r;
            if (row < N_NODES)
                Y[(size_t)row * COUT + nt * 16 + m] = f2fp8(acc[nt][r]);
        }
    }
    #pragma unroll
    for (int r = 0; r < 4; r++) {
        int row = rbase + quad * 4 + r;
        if (row >= N_NODES) continue;
        float v = acc[NTO][r];
        if (m < 8) als[row * 8 + m] = v;
        else       ald[row * 8 + (m - 8)] = v;
    }
}

// ---------------- merged: gemm1 blocks FIRST, then fill blocks --------------
// All GEMM_B gemm blocks fit the initial resident wave (~2048 blocks), drain
// in ~25us; fill's 13288 blocks backfill. GOFF%8==0 keeps fill partition p ==
// blockIdx%8 alignment (cursor/srclist slice locality per XCD) from R18.

__global__ __launch_bounds__(256) void fill_gemm1(
        const int* __restrict__ ei, int* __restrict__ cursor,
        int* __restrict__ srclist,
        const float* __restrict__ x, const bfu* __restrict__ WtX1,
        u8* __restrict__ Y, float* __restrict__ als, float* __restrict__ ald) {
    int bid = blockIdx.x;
    if (bid < GOFF) {
        if (bid < GEMM_B)
            gemm1_body(bid, x, WtX1, Y, als, ald);
        return;
    }
    fill_body(bid - GOFF, ei, cursor, srclist);
}

// ---------------- fused agg + gemm ------------------------------------------
// 128 threads / 32 dst rows per block (R18 form).
// Phase 1 (agg): 2 waves x 8 dst x 2 iters = 32 dst rows -> bf16 in LDS.
//   Gather loop unrolled 4-wide (8 outstanding loads/lane).
//   LDS: 32 rows x 16 granules(16B), swizzled gran ^= (row&7) both sides.
// Phase 2 (gemm): 32-row MFMA tile (2 waves x 16 rows), A from LDS.

__device__ inline void unpack_fma(uint4 u, float w, float* a) {
    f32x2 p;
    p = __builtin_amdgcn_cvt_pk_f32_fp8((int)u.x, false); a[0]=fmaf(w,p[0],a[0]);  a[1]=fmaf(w,p[1],a[1]);
    p = __builtin_amdgcn_cvt_pk_f32_fp8((int)u.x, true);  a[2]=fmaf(w,p[0],a[2]);  a[3]=fmaf(w,p[1],a[3]);
    p = __builtin_amdgcn_cvt_pk_f32_fp8((int)u.y, false); a[4]=fmaf(w,p[0],a[4]);  a[5]=fmaf(w,p[1],a[5]);
    p = __builtin_amdgcn_cvt_pk_f32_fp8((int)u.y, true);  a[6]=fmaf(w,p[0],a[6]);  a[7]=fmaf(w,p[1],a[7]);
    p = __builtin_amdgcn_cvt_pk_f32_fp8((int)u.z, false); a[8]=fmaf(w,p[0],a[8]);  a[9]=fmaf(w,p[1],a[9]);
    p = __builtin_amdgcn_cvt_pk_f32_fp8((int)u.z, true);  a[10]=fmaf(w,p[0],a[10]); a[11]=fmaf(w,p[1],a[11]);
    p = __builtin_amdgcn_cvt_pk_f32_fp8((int)u.w, false); a[12]=fmaf(w,p[0],a[12]); a[13]=fmaf(w,p[1],a[13]);
    p = __builtin_amdgcn_cvt_pk_f32_fp8((int)u.w, true);  a[14]=fmaf(w,p[0],a[14]); a[15]=fmaf(w,p[1],a[15]);
}

template<int NTO>
__global__ __launch_bounds__(128) void fused_agg_gemm(
        const u8* __restrict__ Hin,       // N x 128 fp8 (prev gemm out)
        const float* __restrict__ als_in, // N x 8
        const float* __restrict__ ald_in, // N x 8
        const int* __restrict__ deg, const int* __restrict__ srclist,
        const float* __restrict__ bias,   // 128 (prev layer bias)
        const bfu* __restrict__ Wt,       // (NTO+1)*16 x 128 bf16
        u8* __restrict__ Yout,            // N x NTO*16 fp8
        float* __restrict__ als_out, float* __restrict__ ald_out) {
    __shared__ uint4 ldsb[32 * 16];       // 8 KB
    int t    = threadIdx.x;
    int wid  = t >> 6;                    // 0..1
    int lane = t & 63;
    int sub  = lane >> 3;
    int li   = lane & 7;
    int rbase = blockIdx.x * 32;

    // ---- phase 1: aggregate 32 dst nodes into LDS ----
    #pragma unroll
    for (int it = 0; it < 2; ++it) {
        int dl = wid * 16 + it * 8 + sub;          // 0..31
        int d  = rbase + dl;                       // exact: N % 32 == 0
        {
            int c0 = li * 16;
            float ad = ald_in[d * 8 + li];
            const int* sl = srclist + d * CAP;
            int n = deg[d]; n = n < CAP ? n : CAP;
            float a[16];
            #pragma unroll
            for (int k = 0; k < 16; ++k) a[k] = 0.f;
            float den = 0.f;
            int j = 0;
            for (; j + 4 <= n; j += 4) {
                int s0 = sl[j], s1 = sl[j+1], s2 = sl[j+2], s3 = sl[j+3];
                uint4 u0 = *(const uint4*)(Hin + (size_t)s0 * 128 + c0);
                uint4 u1 = *(const uint4*)(Hin + (size_t)s1 * 128 + c0);
                uint4 u2 = *(const uint4*)(Hin + (size_t)s2 * 128 + c0);
                uint4 u3 = *(const uint4*)(Hin + (size_t)s3 * 128 + c0);
                float x0 = als_in[s0 * 8 + li], x1 = als_in[s1 * 8 + li];
                float x2 = als_in[s2 * 8 + li], x3 = als_in[s3 * 8 + li];
                float l0 = x0 + ad; l0 = fmaxf(l0, NEG * l0); float w0 = __expf(l0);
                float l1 = x1 + ad; l1 = fmaxf(l1, NEG * l1); float w1 = __expf(l1);
                float l2 = x2 + ad; l2 = fmaxf(l2, NEG * l2); float w2 = __expf(l2);
                float l3 = x3 + ad; l3 = fmaxf(l3, NEG * l3); float w3 = __expf(l3);
                den += (w0 + w1) + (w2 + w3);
                unpack_fma(u0, w0, a);
                unpack_fma(u1, w1, a);
                unpack_fma(u2, w2, a);
                unpack_fma(u3, w3, a);
            }
            if (j + 2 <= n) {
                int s0 = sl[j], s1 = sl[j + 1];
                uint4 u0 = *(const uint4*)(Hin + (size_t)s0 * 128 + c0);
                uint4 u1 = *(const uint4*)(Hin + (size_t)s1 * 128 + c0);
                float x0 = als_in[s0 * 8 + li], x1 = als_in[s1 * 8 + li];
                float l0 = x0 + ad; l0 = fmaxf(l0, NEG * l0); float w0 = __expf(l0);
                float l1 = x1 + ad; l1 = fmaxf(l1, NEG * l1); float w1 = __expf(l1);
                den += w0 + w1;
                unpack_fma(u0, w0, a);
                unpack_fma(u1, w1, a);
                j += 2;
            }
            if (j < n) {
                int s0 = sl[j];
                uint4 u0 = *(const uint4*)(Hin + (size_t)s0 * 128 + c0);
                float x0 = als_in[s0 * 8 + li];
                float l0 = x0 + ad; l0 = fmaxf(l0, NEG * l0); float w0 = __expf(l0);
                den += w0;
                unpack_fma(u0, w0, a);
            }
            float r = 1.f / den;
            unsigned dw[8];
            #pragma unroll
            for (int k = 0; k < 8; ++k) {
                float e0 = fmaxf(fmaf(a[2*k],   r, bias[c0 + 2*k]),   0.f);
                float e1 = fmaxf(fmaf(a[2*k+1], r, bias[c0 + 2*k+1]), 0.f);
                dw[k] = (unsigned)f2bf(e0) | ((unsigned)f2bf(e1) << 16);
            }
            uint4 st0 = {dw[0], dw[1], dw[2], dw[3]};
            uint4 st1 = {dw[4], dw[5], dw[6], dw[7]};
            int sw = dl & 7;
            ldsb[dl * 16 + ((li * 2)     ^ sw)] = st0;
            ldsb[dl * 16 + ((li * 2 + 1) ^ sw)] = st1;
        }
    }
    __syncthreads();

    // ---- phase 2: 32-row MFMA gemm, A from LDS ----
    constexpr int COUT = NTO * 16;
    int m = lane & 15, quad = lane >> 4;
    int lr = wid * 16 + m;
    int lb = lr * 16, sw = lr & 7;
    bf16x8 a0 = *(const bf16x8*)&ldsb[lb + ((quad)      ^ sw)];
    bf16x8 a1 = *(const bf16x8*)&ldsb[lb + ((quad + 4)  ^ sw)];
    bf16x8 a2 = *(const bf16x8*)&ldsb[lb + ((quad + 8)  ^ sw)];
    bf16x8 a3 = *(const bf16x8*)&ldsb[lb + ((quad + 12) ^ sw)];

    const bfu* Bp = Wt + (size_t)m * 128 + quad * 8;
    f32x4 acc[NTO + 1];
    #pragma unroll
    for (int nt = 0; nt <= NTO; nt++) {
        const bfu* Bn = Bp + nt * 16 * 128;
        f32x4 c = {0.f, 0.f, 0.f, 0.f};
        c = __builtin_amdgcn_mfma_f32_16x16x32_bf16(a0, *(const bf16x8*)(Bn),      c, 0, 0, 0);
        c = __builtin_amdgcn_mfma_f32_16x16x32_bf16(a1, *(const bf16x8*)(Bn + 32), c, 0, 0, 0);
        c = __builtin_amdgcn_mfma_f32_16x16x32_bf16(a2, *(const bf16x8*)(Bn + 64), c, 0, 0, 0);
        c = __builtin_amdgcn_mfma_f32_16x16x32_bf16(a3, *(const bf16x8*)(Bn + 96), c, 0, 0, 0);
        acc[nt] = c;
    }

    #pragma unroll
    for (int nt = 0; nt < NTO; nt++) {
        #pragma unroll
        for (int r = 0; r < 4; r++) {
            int row = rbase + wid * 16 + quad * 4 + r;
            Yout[(size_t)row * COUT + nt * 16 + m] = f2fp8(acc[nt][r]);
        }
    }
    #pragma unroll
    for (int r = 0; r < 4; r++) {
        int row = rbase + wid * 16 + quad * 4 + r;
        float v = acc[NTO][r];
        if constexpr (NTO == 8) {
            if (m < 8) als_out[row * 8 + m] = v;
            else       ald_out[row * 8 + (m - 8)] = v;
        } else {
            if (m == 0) als_out[row] = v;
            else if (m == 1) ald_out[row] = v;
        }
    }
}

// ---------------- agg32 + fused mean pool (final layer) ---------------------

__global__ __launch_bounds__(256) void agg32(const u8* __restrict__ Hb,
        const float* __restrict__ als, const float* __restrict__ ald,
        const int* __restrict__ deg, const int* __restrict__ srclist,
        const float* __restrict__ bias, float* __restrict__ outp) {
    __shared__ float lds[4][32];
    int t    = threadIdx.x;
    int wid  = t >> 6;
    int lane = t & 63;
    int sub  = lane >> 3;
    int li   = lane & 7;
    int d    = blockIdx.x * 32 + wid * 8 + sub;   // exact
    int c0 = li * 4;
    float adv = ald[d];
    const int* sl = srclist + d * CAP;
    int n = deg[d]; n = n < CAP ? n : CAP;
    float a0=0.f,a1=0.f,a2=0.f,a3=0.f,den=0.f;
    int j = 0;
    for (; j + 4 <= n; j += 4) {
        int s0 = sl[j], s1 = sl[j+1], s2 = sl[j+2], s3 = sl[j+3];
        unsigned u0 = *(const unsigned*)(Hb + (size_t)s0 * 32 + c0);
        unsigned u1 = *(const unsigned*)(Hb + (size_t)s1 * 32 + c0);
        unsigned u2 = *(const unsigned*)(Hb + (size_t)s2 * 32 + c0);
        unsigned u3 = *(const unsigned*)(Hb + (size_t)s3 * 32 + c0);
        float x0 = als[s0], x1 = als[s1], x2 = als[s2], x3 = als[s3];
        float l0 = x0 + adv; l0 = fmaxf(l0, NEG*l0); float w0 = __expf(l0);
        float l1 = x1 + adv; l1 = fmaxf(l1, NEG*l1); float w1 = __expf(l1);
        float l2 = x2 + adv; l2 = fmaxf(l2, NEG*l2); float w2 = __expf(l2);
        float l3 = x3 + adv; l3 = fmaxf(l3, NEG*l3); float w3 = __expf(l3);
        den += (w0 + w1) + (w2 + w3);
        f32x2 p;
        p = __builtin_amdgcn_cvt_pk_f32_fp8((int)u0, false); a0=fmaf(w0,p[0],a0); a1=fmaf(w0,p[1],a1);
        p = __builtin_amdgcn_cvt_pk_f32_fp8((int)u0, true);  a2=fmaf(w0,p[0],a2); a3=fmaf(w0,p[1],a3);
        p = __builtin_amdgcn_cvt_pk_f32_fp8((int)u1, false); a0=fmaf(w1,p[0],a0); a1=fmaf(w1,p[1],a1);
        p = __builtin_amdgcn_cvt_pk_f32_fp8((int)u1, true);  a2=fmaf(w1,p[0],a2); a3=fmaf(w1,p[1],a3);
        p = __builtin_amdgcn_cvt_pk_f32_fp8((int)u2, false); a0=fmaf(w2,p[0],a0); a1=fmaf(w2,p[1],a1);
        p = __builtin_amdgcn_cvt_pk_f32_fp8((int)u2, true);  a2=fmaf(w2,p[0],a2); a3=fmaf(w2,p[1],a3);
        p = __builtin_amdgcn_cvt_pk_f32_fp8((int)u3, false); a0=fmaf(w3,p[0],a0); a1=fmaf(w3,p[1],a1);
        p = __builtin_amdgcn_cvt_pk_f32_fp8((int)u3, true);  a2=fmaf(w3,p[0],a2); a3=fmaf(w3,p[1],a3);
    }
    for (; j < n; ++j) {
        int s0 = sl[j];
        unsigned u0 = *(const unsigned*)(Hb + (size_t)s0 * 32 + c0);
        float x0 = als[s0];
        float l0 = x0 + adv; l0 = fmaxf(l0, NEG*l0); float w0 = __expf(l0);
        den += w0;
        f32x2 p;
        p = __builtin_amdgcn_cvt_pk_f32_fp8((int)u0, false); a0=fmaf(w0,p[0],a0); a1=fmaf(w0,p[1],a1);
        p = __builtin_amdgcn_cvt_pk_f32_fp8((int)u0, true);  a2=fmaf(w0,p[0],a2); a3=fmaf(w0,p[1],a3);
    }
    float r = 1.f / den;
    float4 bv = *(const float4*)&bias[c0];
    float o0 = fmaf(a0, r, bv.x), o1 = fmaf(a1, r, bv.y);
    float o2 = fmaf(a2, r, bv.z), o3 = fmaf(a3, r, bv.w);
    #pragma unroll
    for (int mask = 8; mask < 64; mask <<= 1) {
        o0 += __shfl_xor(o0, mask);
        o1 += __shfl_xor(o1, mask);
        o2 += __shfl_xor(o2, mask);
        o3 += __shfl_xor(o3, mask);
    }
    if (sub == 0) {
        lds[wid][c0]     = o0;
        lds[wid][c0 + 1] = o1;
        lds[wid][c0 + 2] = o2;
        lds[wid][c0 + 3] = o3;
    }
    __syncthreads();
    if (t < 32)
        atomicAdd(&outp[t],
            (lds[0][t] + lds[1][t] + lds[2][t] + lds[3][t]) * (1.0f / N_NODES));
}

// ---------------- launch ----------------

extern "C" void kernel_launch(void* const* d_in, const int* in_sizes, int n_in,
                              void* d_out, int out_size, void* d_ws, size_t ws_size,
                              hipStream_t stream) {
    (void)in_sizes; (void)n_in; (void)out_size; (void)ws_size;
    const float* x   = (const float*)d_in[0];
    const int*   ei  = (const int*)d_in[1];
    const float* W1  = (const float*)d_in[2];
    const float* as1 = (const float*)d_in[3];
    const float* ad1 = (const float*)d_in[4];
    const float* b1  = (const float*)d_in[5];
    const float* W2  = (const float*)d_in[6];
    const float* as2 = (const float*)d_in[7];
    const float* ad2 = (const float*)d_in[8];
    const float* b2  = (const float*)d_in[9];
    const float* W3  = (const float*)d_in[10];
    const float* as3 = (const float*)d_in[11];
    const float* ad3 = (const float*)d_in[12];
    const float* b3  = (const float*)d_in[13];

    char* ws = (char*)d_ws;
    size_t off = 0;
    auto carve = [&](size_t bytes) { void* p = ws + off; off += (bytes + 255) & ~size_t(255); return p; };
    u8*    bufHa   = (u8*)carve(size_t(N_NODES) * 128);        // L1 feat fp8; reused for L3 feat (32B rows)
    u8*    bufHb   = (u8*)carve(size_t(N_NODES) * 128);        // L2 feat fp8
    float* alsA    = (float*)carve(size_t(N_NODES) * 8 * 4);   // L1 logits; reused for L3
    float* aldA    = (float*)carve(size_t(N_NODES) * 8 * 4);
    float* alsB    = (float*)carve(size_t(N_NODES) * 8 * 4);   // L2 logits
    float* aldB    = (float*)carve(size_t(N_NODES) * 8 * 4);
    int*   cursor  = (int*)carve(size_t(N_NODES) * 4);
    bfu*   WtX1    = (bfu*)carve(144 * 128 * 2);
    bfu*   WtX2    = (bfu*)carve(144 * 128 * 2);
    bfu*   WtX3    = (bfu*)carve(48 * 128 * 2);
    int*   srclist = (int*)carve(size_t(N_NODES) * CAP * 4);

    // prep (WtX*) + cursor zero + d_out zero -- one tiny dispatch
    prep_cursor<<<PREP_B, 256, 0, stream>>>(W1, W2, W3,
        as1, ad1, as2, ad2, as3, ad3, WtX1, WtX2, WtX3, cursor, (float*)d_out);

    // gemm1 (first 1563 blocks, drain fast) + CSR fill (backfills behind)
    fill_gemm1<<<FG_GRID, 256, 0, stream>>>(ei, cursor, srclist,
        x, WtX1, bufHa, alsA, aldA);

    // layer 2: fused agg(L1) + gemm2 (reads bufHa, writes bufHb + logits B)
    fused_agg_gemm<8><<<FUSE_B, 128, 0, stream>>>(bufHa, alsA, aldA,
        cursor, srclist, b1, WtX2, bufHb, alsB, aldB);

    // layer 3: fused agg(L2) + gemm3 (reads bufHb, writes bufHa(32B rows) + logits A)
    fused_agg_gemm<2><<<FUSE_B, 128, 0, stream>>>(bufHb, alsB, aldB,
        cursor, srclist, b2, WtX3, bufHa, alsA, aldA);

    // final aggregation + mean pool
    agg32<<<AGG32_B, 256, 0, stream>>>(bufHa, alsA, aldA, cursor, srclist, b3, (float*)d_out);
}